// Round 6
// baseline (1397.381 us; speedup 1.0000x reference)
//
#include <hip/hip_runtime.h>
#include <hip/hip_bf16.h>
#include <math.h>

#define N_NODES 100000
#define N_EDGES 1000000
#define F_IN    128
#define ED_DIM  16
#define H_HEADS 5
#define C_CH    16
#define HC      80
#define NEG_SLOPE 0.2f

#define SCAN_B 256
#define SCAN_G ((N_NODES + SCAN_B - 1) / SCAN_B)   // 391
#define DBIN 64

// ================= CSR build (graph is static across layers) =================

__global__ void k_hist(const int* __restrict__ dst, int* __restrict__ count) {
    const int e = blockIdx.x * 256 + threadIdx.x;
    if (e < N_EDGES) atomicAdd(count + dst[e], 1);
}

__global__ __launch_bounds__(SCAN_B) void k_part(const int* __restrict__ count,
                                                 int* __restrict__ partial) {
    const int i = blockIdx.x * SCAN_B + threadIdx.x;
    int v = (i < N_NODES) ? count[i] : 0;
    const int lane = threadIdx.x & 63;
    const int w    = threadIdx.x >> 6;
    __shared__ int ws[SCAN_B / 64];
    #pragma unroll
    for (int o = 32; o > 0; o >>= 1) v += __shfl_down(v, o, 64);
    if (lane == 0) ws[w] = v;
    __syncthreads();
    if (threadIdx.x == 0) {
        int s = 0;
        #pragma unroll
        for (int k = 0; k < SCAN_B / 64; ++k) s += ws[k];
        partial[blockIdx.x] = s;
    }
}

__global__ __launch_bounds__(512) void k_scanp(const int* __restrict__ partial,
                                               int* __restrict__ blockoff,
                                               int* __restrict__ rowstart) {
    __shared__ int s[512];
    const int t = threadIdx.x;
    int v = (t < SCAN_G) ? partial[t] : 0;
    s[t] = v;
    __syncthreads();
    for (int o = 1; o < 512; o <<= 1) {
        int u = (t >= o) ? s[t - o] : 0;
        __syncthreads();
        s[t] += u;
        __syncthreads();
    }
    if (t < SCAN_G) blockoff[t] = (t == 0) ? 0 : s[t - 1];
    if (t == 0) rowstart[N_NODES] = s[511];
}

__global__ __launch_bounds__(SCAN_B) void k_apply(const int* __restrict__ count,
                                                  const int* __restrict__ blockoff,
                                                  int* __restrict__ rowstart) {
    __shared__ int s[SCAN_B];
    const int i = blockIdx.x * SCAN_B + threadIdx.x;
    const int t = threadIdx.x;
    const int v = (i < N_NODES) ? count[i] : 0;
    s[t] = v;
    __syncthreads();
    for (int o = 1; o < SCAN_B; o <<= 1) {
        int u = (t >= o) ? s[t - o] : 0;
        __syncthreads();
        s[t] += u;
        __syncthreads();
    }
    if (i < N_NODES) rowstart[i] = blockoff[blockIdx.x] + (s[t] - v);
}

__global__ void k_place(const int* __restrict__ src, const int* __restrict__ dst,
                        const int* __restrict__ rowstart, int* __restrict__ cursor,
                        int* __restrict__ perm, int* __restrict__ src_s) {
    const int e = blockIdx.x * 256 + threadIdx.x;
    if (e >= N_EDGES) return;
    const int d = dst[e];
    const int pos = rowstart[d] + atomicAdd(cursor + d, 1);
    perm[pos]  = e;
    src_s[pos] = src[e];
}

// pre-permute edge attrs into CSR order (once; reused by all 3 layers)
__global__ void k_permea(const float* __restrict__ eattr, const int* __restrict__ perm,
                         float* __restrict__ out) {
    const int i = blockIdx.x * 256 + threadIdx.x;   // over E*4 float4s
    if (i >= N_EDGES * 4) return;
    const int p = i >> 2;
    const int r = i & 3;
    const int e = perm[p];
    ((float4*)out)[i] = ((const float4*)eattr)[(size_t)e * 4 + r];
}

// ====== degree-bucket counting sort of nodes (descending degree) =============
__global__ __launch_bounds__(256) void k_deghist(const int* __restrict__ cnt,
                                                 int* __restrict__ dhist) {
    __shared__ int lh[DBIN];
    const int t = threadIdx.x;
    if (t < DBIN) lh[t] = 0;
    __syncthreads();
    const int n = blockIdx.x * 256 + t;
    if (n < N_NODES) atomicAdd(&lh[min(cnt[n], DBIN - 1)], 1);
    __syncthreads();
    if (t < DBIN && lh[t] > 0) atomicAdd(dhist + t, lh[t]);
}

__global__ void k_degoff(const int* __restrict__ dhist, int* __restrict__ dcur) {
    if (threadIdx.x == 0) {
        int off = 0;
        for (int b = DBIN - 1; b >= 0; --b) { dcur[b] = off; off += dhist[b]; }
    }
}

__global__ __launch_bounds__(256) void k_degplace(const int* __restrict__ cnt,
                                                  int* __restrict__ dcur,
                                                  int* __restrict__ nodeord) {
    __shared__ int lh[DBIN];
    __shared__ int base[DBIN];
    const int t = threadIdx.x;
    if (t < DBIN) lh[t] = 0;
    __syncthreads();
    const int n = blockIdx.x * 256 + t;
    int b = 0, r = 0;
    if (n < N_NODES) {
        b = min(cnt[n], DBIN - 1);
        r = atomicAdd(&lh[b], 1);
    }
    __syncthreads();
    if (t < DBIN && lh[t] > 0) base[t] = atomicAdd(dcur + t, lh[t]);
    __syncthreads();
    if (n < N_NODES) nodeord[base[b] + r] = n;
}

// ====== fused dual node transform: xl = A@WL^T+bL, xr = A@WR^T+bR ============
template<int DIN>
__global__ __launch_bounds__(320) void k_xform2(
    const float* __restrict__ A,
    const float* __restrict__ WL, const float* __restrict__ bL,
    const float* __restrict__ WR, const float* __restrict__ bR,
    float* __restrict__ outL, float* __restrict__ outR, int nn) {
    __shared__ float As[16][68];
    __shared__ float WsL[16][80];
    __shared__ float WsR[16][80];
    const int t  = threadIdx.x;
    const int n0 = blockIdx.x * 64;
    const int tn = (t & 15) * 4;
    const int tj = (t >> 4) * 4;
    float4 accL[4], accR[4];
    #pragma unroll
    for (int u = 0; u < 4; ++u) {
        accL[u] = make_float4(0.f, 0.f, 0.f, 0.f);
        accR[u] = make_float4(0.f, 0.f, 0.f, 0.f);
    }

    for (int k0 = 0; k0 < DIN; k0 += 16) {
        __syncthreads();
        for (int i = t; i < 64*16; i += 320) {
            int nl = i >> 4, kk = i & 15;
            int n = n0 + nl;
            As[kk][nl] = (n < nn) ? A[(size_t)n*DIN + k0 + kk] : 0.f;
        }
        for (int i = t; i < 80*16; i += 320) {
            int jj = i >> 4, kk = i & 15;
            WsL[kk][jj] = WL[(size_t)jj*DIN + k0 + kk];
            WsR[kk][jj] = WR[(size_t)jj*DIN + k0 + kk];
        }
        __syncthreads();
        #pragma unroll
        for (int k = 0; k < 16; ++k) {
            const float4 av = *(const float4*)&As[k][tn];
            const float4 wl = *(const float4*)&WsL[k][tj];
            const float4 wr = *(const float4*)&WsR[k][tj];
            accL[0].x += av.x*wl.x; accL[0].y += av.x*wl.y; accL[0].z += av.x*wl.z; accL[0].w += av.x*wl.w;
            accL[1].x += av.y*wl.x; accL[1].y += av.y*wl.y; accL[1].z += av.y*wl.z; accL[1].w += av.y*wl.w;
            accL[2].x += av.z*wl.x; accL[2].y += av.z*wl.y; accL[2].z += av.z*wl.z; accL[2].w += av.z*wl.w;
            accL[3].x += av.w*wl.x; accL[3].y += av.w*wl.y; accL[3].z += av.w*wl.z; accL[3].w += av.w*wl.w;
            accR[0].x += av.x*wr.x; accR[0].y += av.x*wr.y; accR[0].z += av.x*wr.z; accR[0].w += av.x*wr.w;
            accR[1].x += av.y*wr.x; accR[1].y += av.y*wr.y; accR[1].z += av.y*wr.z; accR[1].w += av.y*wr.w;
            accR[2].x += av.z*wr.x; accR[2].y += av.z*wr.y; accR[2].z += av.z*wr.z; accR[2].w += av.z*wr.w;
            accR[3].x += av.w*wr.x; accR[3].y += av.w*wr.y; accR[3].z += av.w*wr.z; accR[3].w += av.w*wr.w;
        }
    }
    const float4 bvL = *(const float4*)(bL + tj);
    const float4 bvR = *(const float4*)(bR + tj);
    #pragma unroll
    for (int u = 0; u < 4; ++u) {
        int n = n0 + tn + u;
        if (n < nn) {
            float4 o;
            o.x = accL[u].x + bvL.x; o.y = accL[u].y + bvL.y;
            o.z = accL[u].z + bvL.z; o.w = accL[u].w + bvL.w;
            *(float4*)(outL + (size_t)n*HC + tj) = o;
            o.x = accR[u].x + bvR.x; o.y = accR[u].y + bvR.y;
            o.z = accR[u].z + bvR.z; o.w = accR[u].w + bvR.w;
            *(float4*)(outR + (size_t)n*HC + tj) = o;
        }
    }
}

// ====== fused attention, 2 nodes per 80-thread group ========================
// thread = channel c (head = c>>4); group handles nodeord[2*gidx], [2*gidx+1]
// (adjacent in degree-sorted order -> equal segment length). Two independent
// gather/compute chains per thread double MLP+ILP. Out-of-range iterations
// use clamped (valid) indices, predicated via pt *= 0.
template<bool SORTED>
__global__ __launch_bounds__(320) void k_fused2(
    const float* __restrict__ xl, const float* __restrict__ xr,
    const float* __restrict__ ea,   // eattr_s if SORTED, raw eattr otherwise
    const float* __restrict__ we, const float* __restrict__ att,
    const int* __restrict__ perm, const int* __restrict__ src_s,
    const int* __restrict__ rowstart, const int* __restrict__ nodeord,
    const float* __restrict__ bias, float* __restrict__ out, int relu) {
    const int t = threadIdx.x;
    const int group = t / 80;
    const int c = t - group * 80;
    const int idx = (blockIdx.x * 4 + group) * 2;
    if (idx >= N_NODES) return;
    const int n1 = nodeord[idx];
    const bool has2 = (idx + 1) < N_NODES;
    const int n2 = has2 ? nodeord[idx + 1] : n1;

    const float4* w4 = (const float4*)(we + c * ED_DIM);
    const float4 w0 = w4[0], w1 = w4[1], w2 = w4[2], w3 = w4[3];
    const float attc = att[c];
    const float bc   = bias[c];
    const float xr1  = xr[(size_t)n1 * HC + c];
    const float xr2  = xr[(size_t)n2 * HC + c];

    const int rs1 = rowstart[n1];
    const int d1  = rowstart[n1 + 1] - rs1;
    const int rs2 = rowstart[n2];
    const int d2  = has2 ? (rowstart[n2 + 1] - rs2) : 0;
    const int mx  = max(d1, d2);

    float acc1 = 0.f, l1 = 0.f, acc2 = 0.f, l2 = 0.f;

    if (mx > 0) {
        int q1 = min(rs1, N_EDGES - 1);
        int q2 = min(rs2, N_EDGES - 1);
        int s1 = src_s[q1], s2 = src_s[q2];
        float xl1 = xl[(size_t)s1 * HC + c];
        float xl2 = xl[(size_t)s2 * HC + c];
        int e1 = SORTED ? q1 : perm[q1];
        int e2 = SORTED ? q2 : perm[q2];

        for (int i = 0; i < mx; ++i) {
            const float cxl1 = xl1, cxl2 = xl2;
            const float4* A1 = (const float4*)(ea + (size_t)e1 * ED_DIM);
            const float4* A2 = (const float4*)(ea + (size_t)e2 * ED_DIM);
            const float4 a10 = A1[0], a11 = A1[1], a12 = A1[2], a13 = A1[3];
            const float4 a20 = A2[0], a21 = A2[1], a22 = A2[2], a23 = A2[3];
            if (i + 1 < mx) {  // prefetch the gather chain one iteration ahead
                const int i1 = (d1 > 0) ? min(i + 1, d1 - 1) : 0;
                const int i2 = (d2 > 0) ? min(i + 1, d2 - 1) : 0;
                q1 = min(rs1 + i1, N_EDGES - 1);
                q2 = min(rs2 + i2, N_EDGES - 1);
                s1 = src_s[q1]; s2 = src_s[q2];
                xl1 = xl[(size_t)s1 * HC + c];
                xl2 = xl[(size_t)s2 * HC + c];
                e1 = SORTED ? q1 : perm[q1];
                e2 = SORTED ? q2 : perm[q2];
            }
            float em1 = a10.x*w0.x + a10.y*w0.y + a10.z*w0.z + a10.w*w0.w
                      + a11.x*w1.x + a11.y*w1.y + a11.z*w1.z + a11.w*w1.w
                      + a12.x*w2.x + a12.y*w2.y + a12.z*w2.z + a12.w*w2.w
                      + a13.x*w3.x + a13.y*w3.y + a13.z*w3.z + a13.w*w3.w;
            float em2 = a20.x*w0.x + a20.y*w0.y + a20.z*w0.z + a20.w*w0.w
                      + a21.x*w1.x + a21.y*w1.y + a21.z*w1.z + a21.w*w1.w
                      + a22.x*w2.x + a22.y*w2.y + a22.z*w2.z + a22.w*w2.w
                      + a23.x*w3.x + a23.y*w3.y + a23.z*w3.z + a23.w*w3.w;
            float v1 = cxl1 + xr1 + em1;
            float v2 = cxl2 + xr2 + em2;
            v1 = fmaxf(v1, 0.f) + NEG_SLOPE * fminf(v1, 0.f);
            v2 = fmaxf(v2, 0.f) + NEG_SLOPE * fminf(v2, 0.f);
            v1 *= attc;
            v2 *= attc;
            v1 += __shfl_xor(v1, 1);  v2 += __shfl_xor(v2, 1);
            v1 += __shfl_xor(v1, 2);  v2 += __shfl_xor(v2, 2);
            v1 += __shfl_xor(v1, 4);  v2 += __shfl_xor(v2, 4);
            v1 += __shfl_xor(v1, 8);  v2 += __shfl_xor(v2, 8);
            const float pt1 = __expf(v1) * ((i < d1) ? 1.f : 0.f);
            const float pt2 = __expf(v2) * ((i < d2) ? 1.f : 0.f);
            acc1 += pt1 * cxl1;  l1 += pt1;
            acc2 += pt2 * cxl2;  l2 += pt2;
        }
    }
    float o1 = acc1 / (l1 + 1e-16f) + bc;
    if (relu) o1 = fmaxf(o1, 0.f);
    out[(size_t)n1 * HC + c] = o1;
    if (has2) {
        float o2 = acc2 / (l2 + 1e-16f) + bc;
        if (relu) o2 = fmaxf(o2, 0.f);
        out[(size_t)n2 * HC + c] = o2;
    }
}

extern "C" void kernel_launch(void* const* d_in, const int* in_sizes, int n_in,
                              void* d_out, int out_size, void* d_ws, size_t ws_size,
                              hipStream_t stream) {
    (void)in_sizes; (void)n_in; (void)out_size;
    const float* x     = (const float*)d_in[0];
    const int*   ei    = (const int*)d_in[1];
    const float* eattr = (const float*)d_in[2];
    const int* srcp = ei;
    const int* dstp = ei + N_EDGES;

    // workspace layout
    float* h      = (float*)d_ws;                            // N*80
    float* xl     = h  + (size_t)N_NODES*HC;                 // N*80
    float* xr     = xl + (size_t)N_NODES*HC;                 // N*80
    int* rowstart = (int*)(xr + (size_t)N_NODES*HC);         // N+1
    int* cursor   = rowstart + (N_NODES + 1);                // N
    int* perm     = cursor + N_NODES;                        // E
    int* src_s    = perm + N_EDGES;                          // E
    int* partial  = src_s + N_EDGES;                         // SCAN_G
    int* blockoff = partial + SCAN_G;                        // SCAN_G
    int* dhist    = blockoff + SCAN_G;                       // DBIN
    int* dcur     = dhist + DBIN;                            // DBIN
    int* nodeord  = dcur + DBIN;                             // N
    float* eattr_s = (float*)(nodeord + N_NODES);            // E*16 (optional)
    float* outp   = (float*)d_out;

    const size_t need_sorted = (size_t)((char*)(eattr_s + (size_t)N_EDGES * ED_DIM) - (char*)d_ws);
    const bool use_sorted = (ws_size >= need_sorted);

    const dim3 bx(320);
    const dim3 gx((N_NODES + 63) / 64);
    const dim3 gf2((N_NODES + 7) / 8);
    const dim3 geb((N_EDGES + 255) / 256);
    const dim3 gnb((N_NODES + 255) / 256);

    // ---- build CSR by destination + degree-sorted node order (once) ----
    hipMemsetAsync(cursor, 0, (size_t)N_NODES * sizeof(int), stream);
    hipMemsetAsync(dhist, 0, DBIN * sizeof(int), stream);
    k_hist<<<geb, 256, 0, stream>>>(dstp, cursor);
    k_part<<<SCAN_G, SCAN_B, 0, stream>>>(cursor, partial);
    k_scanp<<<1, 512, 0, stream>>>(partial, blockoff, rowstart);
    k_apply<<<SCAN_G, SCAN_B, 0, stream>>>(cursor, blockoff, rowstart);
    k_deghist<<<gnb, 256, 0, stream>>>(cursor, dhist);
    k_degoff<<<1, 64, 0, stream>>>(dhist, dcur);
    k_degplace<<<gnb, 256, 0, stream>>>(cursor, dcur, nodeord);
    hipMemsetAsync(cursor, 0, (size_t)N_NODES * sizeof(int), stream);
    k_place<<<geb, 256, 0, stream>>>(srcp, dstp, rowstart, cursor, perm, src_s);
    if (use_sorted) {
        k_permea<<<(N_EDGES * 4 + 255) / 256, 256, 0, stream>>>(eattr, perm, eattr_s);
    }

    for (int L = 0; L < 3; ++L) {
        const float* in   = (L == 0) ? x : h;
        float*       oacc = (L == 2) ? outp : h;
        const float* wl   = (const float*)d_in[3 + L*7 + 0];
        const float* bl   = (const float*)d_in[3 + L*7 + 1];
        const float* wr   = (const float*)d_in[3 + L*7 + 2];
        const float* br   = (const float*)d_in[3 + L*7 + 3];
        const float* we   = (const float*)d_in[3 + L*7 + 4];
        const float* att  = (const float*)d_in[3 + L*7 + 5];
        const float* bias = (const float*)d_in[3 + L*7 + 6];

        if (L == 0) {
            k_xform2<F_IN><<<gx, bx, 0, stream>>>(in, wl, bl, wr, br, xl, xr, N_NODES);
        } else {
            k_xform2<HC><<<gx, bx, 0, stream>>>(in, wl, bl, wr, br, xl, xr, N_NODES);
        }
        if (use_sorted) {
            k_fused2<true><<<gf2, bx, 0, stream>>>(xl, xr, eattr_s, we, att, perm,
                                                   src_s, rowstart, nodeord, bias,
                                                   oacc, (L < 2) ? 1 : 0);
        } else {
            k_fused2<false><<<gf2, bx, 0, stream>>>(xl, xr, eattr, we, att, perm,
                                                    src_s, rowstart, nodeord, bias,
                                                    oacc, (L < 2) ? 1 : 0);
        }
    }
}

// Round 7
// 1335.990 us; speedup vs baseline: 1.0460x; 1.0460x over previous
//
#include <hip/hip_runtime.h>
#include <hip/hip_bf16.h>
#include <math.h>

#define N_NODES 100000
#define N_EDGES 1000000
#define F_IN    128
#define ED_DIM  16
#define H_HEADS 5
#define C_CH    16
#define HC      80
#define NEG_SLOPE 0.2f

#define SCAN_B 256
#define SCAN_G ((N_NODES + SCAN_B - 1) / SCAN_B)   // 391
#define DBIN 64

// ================= CSR build (graph is static across layers) =================

__global__ void k_hist(const int* __restrict__ dst, int* __restrict__ count) {
    const int e = blockIdx.x * 256 + threadIdx.x;
    if (e < N_EDGES) atomicAdd(count + dst[e], 1);
}

__global__ __launch_bounds__(SCAN_B) void k_part(const int* __restrict__ count,
                                                 int* __restrict__ partial) {
    const int i = blockIdx.x * SCAN_B + threadIdx.x;
    int v = (i < N_NODES) ? count[i] : 0;
    const int lane = threadIdx.x & 63;
    const int w    = threadIdx.x >> 6;
    __shared__ int ws[SCAN_B / 64];
    #pragma unroll
    for (int o = 32; o > 0; o >>= 1) v += __shfl_down(v, o, 64);
    if (lane == 0) ws[w] = v;
    __syncthreads();
    if (threadIdx.x == 0) {
        int s = 0;
        #pragma unroll
        for (int k = 0; k < SCAN_B / 64; ++k) s += ws[k];
        partial[blockIdx.x] = s;
    }
}

__global__ __launch_bounds__(512) void k_scanp(const int* __restrict__ partial,
                                               int* __restrict__ blockoff,
                                               int* __restrict__ rowstart) {
    __shared__ int s[512];
    const int t = threadIdx.x;
    int v = (t < SCAN_G) ? partial[t] : 0;
    s[t] = v;
    __syncthreads();
    for (int o = 1; o < 512; o <<= 1) {
        int u = (t >= o) ? s[t - o] : 0;
        __syncthreads();
        s[t] += u;
        __syncthreads();
    }
    if (t < SCAN_G) blockoff[t] = (t == 0) ? 0 : s[t - 1];
    if (t == 0) rowstart[N_NODES] = s[511];
}

__global__ __launch_bounds__(SCAN_B) void k_apply(const int* __restrict__ count,
                                                  const int* __restrict__ blockoff,
                                                  int* __restrict__ rowstart) {
    __shared__ int s[SCAN_B];
    const int i = blockIdx.x * SCAN_B + threadIdx.x;
    const int t = threadIdx.x;
    const int v = (i < N_NODES) ? count[i] : 0;
    s[t] = v;
    __syncthreads();
    for (int o = 1; o < SCAN_B; o <<= 1) {
        int u = (t >= o) ? s[t - o] : 0;
        __syncthreads();
        s[t] += u;
        __syncthreads();
    }
    if (i < N_NODES) rowstart[i] = blockoff[blockIdx.x] + (s[t] - v);
}

__global__ void k_place(const int* __restrict__ src, const int* __restrict__ dst,
                        const int* __restrict__ rowstart, int* __restrict__ cursor,
                        int* __restrict__ perm, int* __restrict__ src_s) {
    const int e = blockIdx.x * 256 + threadIdx.x;
    if (e >= N_EDGES) return;
    const int d = dst[e];
    const int pos = rowstart[d] + atomicAdd(cursor + d, 1);
    perm[pos]  = e;
    src_s[pos] = src[e];
}

// pre-permute edge attrs into CSR order (once; reused by all 3 layers)
__global__ void k_permea(const float* __restrict__ eattr, const int* __restrict__ perm,
                         float* __restrict__ out) {
    const int i = blockIdx.x * 256 + threadIdx.x;   // over E*4 float4s
    if (i >= N_EDGES * 4) return;
    const int p = i >> 2;
    const int r = i & 3;
    const int e = perm[p];
    ((float4*)out)[i] = ((const float4*)eattr)[(size_t)e * 4 + r];
}

// ====== degree-bucket counting sort of nodes (descending degree) =============
__global__ __launch_bounds__(256) void k_deghist(const int* __restrict__ cnt,
                                                 int* __restrict__ dhist) {
    __shared__ int lh[DBIN];
    const int t = threadIdx.x;
    if (t < DBIN) lh[t] = 0;
    __syncthreads();
    const int n = blockIdx.x * 256 + t;
    if (n < N_NODES) atomicAdd(&lh[min(cnt[n], DBIN - 1)], 1);
    __syncthreads();
    if (t < DBIN && lh[t] > 0) atomicAdd(dhist + t, lh[t]);
}

__global__ void k_degoff(const int* __restrict__ dhist, int* __restrict__ dcur) {
    if (threadIdx.x == 0) {
        int off = 0;
        for (int b = DBIN - 1; b >= 0; --b) { dcur[b] = off; off += dhist[b]; }
    }
}

__global__ __launch_bounds__(256) void k_degplace(const int* __restrict__ cnt,
                                                  int* __restrict__ dcur,
                                                  int* __restrict__ nodeord) {
    __shared__ int lh[DBIN];
    __shared__ int base[DBIN];
    const int t = threadIdx.x;
    if (t < DBIN) lh[t] = 0;
    __syncthreads();
    const int n = blockIdx.x * 256 + t;
    int b = 0, r = 0;
    if (n < N_NODES) {
        b = min(cnt[n], DBIN - 1);
        r = atomicAdd(&lh[b], 1);
    }
    __syncthreads();
    if (t < DBIN && lh[t] > 0) base[t] = atomicAdd(dcur + t, lh[t]);
    __syncthreads();
    if (n < N_NODES) nodeord[base[b] + r] = n;
}

// ====== fused dual node transform: xl = A@WL^T+bL, xr = A@WR^T+bR ============
template<int DIN>
__global__ __launch_bounds__(320) void k_xform2(
    const float* __restrict__ A,
    const float* __restrict__ WL, const float* __restrict__ bL,
    const float* __restrict__ WR, const float* __restrict__ bR,
    float* __restrict__ outL, float* __restrict__ outR, int nn) {
    __shared__ float As[16][68];
    __shared__ float WsL[16][80];
    __shared__ float WsR[16][80];
    const int t  = threadIdx.x;
    const int n0 = blockIdx.x * 64;
    const int tn = (t & 15) * 4;
    const int tj = (t >> 4) * 4;
    float4 accL[4], accR[4];
    #pragma unroll
    for (int u = 0; u < 4; ++u) {
        accL[u] = make_float4(0.f, 0.f, 0.f, 0.f);
        accR[u] = make_float4(0.f, 0.f, 0.f, 0.f);
    }

    for (int k0 = 0; k0 < DIN; k0 += 16) {
        __syncthreads();
        for (int i = t; i < 64*16; i += 320) {
            int nl = i >> 4, kk = i & 15;
            int n = n0 + nl;
            As[kk][nl] = (n < nn) ? A[(size_t)n*DIN + k0 + kk] : 0.f;
        }
        for (int i = t; i < 80*16; i += 320) {
            int jj = i >> 4, kk = i & 15;
            WsL[kk][jj] = WL[(size_t)jj*DIN + k0 + kk];
            WsR[kk][jj] = WR[(size_t)jj*DIN + k0 + kk];
        }
        __syncthreads();
        #pragma unroll
        for (int k = 0; k < 16; ++k) {
            const float4 av = *(const float4*)&As[k][tn];
            const float4 wl = *(const float4*)&WsL[k][tj];
            const float4 wr = *(const float4*)&WsR[k][tj];
            accL[0].x += av.x*wl.x; accL[0].y += av.x*wl.y; accL[0].z += av.x*wl.z; accL[0].w += av.x*wl.w;
            accL[1].x += av.y*wl.x; accL[1].y += av.y*wl.y; accL[1].z += av.y*wl.z; accL[1].w += av.y*wl.w;
            accL[2].x += av.z*wl.x; accL[2].y += av.z*wl.y; accL[2].z += av.z*wl.z; accL[2].w += av.z*wl.w;
            accL[3].x += av.w*wl.x; accL[3].y += av.w*wl.y; accL[3].z += av.w*wl.z; accL[3].w += av.w*wl.w;
            accR[0].x += av.x*wr.x; accR[0].y += av.x*wr.y; accR[0].z += av.x*wr.z; accR[0].w += av.x*wr.w;
            accR[1].x += av.y*wr.x; accR[1].y += av.y*wr.y; accR[1].z += av.y*wr.z; accR[1].w += av.y*wr.w;
            accR[2].x += av.z*wr.x; accR[2].y += av.z*wr.y; accR[2].z += av.z*wr.z; accR[2].w += av.z*wr.w;
            accR[3].x += av.w*wr.x; accR[3].y += av.w*wr.y; accR[3].z += av.w*wr.z; accR[3].w += av.w*wr.w;
        }
    }
    const float4 bvL = *(const float4*)(bL + tj);
    const float4 bvR = *(const float4*)(bR + tj);
    #pragma unroll
    for (int u = 0; u < 4; ++u) {
        int n = n0 + tn + u;
        if (n < nn) {
            float4 o;
            o.x = accL[u].x + bvL.x; o.y = accL[u].y + bvL.y;
            o.z = accL[u].z + bvL.z; o.w = accL[u].w + bvL.w;
            *(float4*)(outL + (size_t)n*HC + tj) = o;
            o.x = accR[u].x + bvR.x; o.y = accR[u].y + bvR.y;
            o.z = accR[u].z + bvR.z; o.w = accR[u].w + bvR.w;
            *(float4*)(outR + (size_t)n*HC + tj) = o;
        }
    }
}

// ====== fused attention v3: 1 node per 80-thread group ======================
// thread = channel c (head = c>>4). Lane-sliced eattr: thread loads only
// ea[c&15] (4 B); em[c] is assembled via 16 shfl broadcasts within the
// 16-lane segment (segments never straddle a wave since 80 % 16 == 0).
// Gather chain software-pipelined: src 3-ahead, xl 2-ahead, ea 2-ahead ->
// no dependent load inside an iteration, no predication (exact loop bound).
template<bool SORTED>
__global__ __launch_bounds__(320) void k_fused3(
    const float* __restrict__ xl, const float* __restrict__ xr,
    const float* __restrict__ ea,   // eattr_s if SORTED, raw eattr otherwise
    const float* __restrict__ we, const float* __restrict__ att,
    const int* __restrict__ perm, const int* __restrict__ src_s,
    const int* __restrict__ rowstart, const int* __restrict__ nodeord,
    const float* __restrict__ bias, float* __restrict__ out, int relu) {
    const int t = threadIdx.x;
    const int group = t / 80;
    const int c = t - group * 80;
    const int idx = blockIdx.x * 4 + group;
    if (idx >= N_NODES) return;
    const int n = nodeord[idx];

    const float4* w4 = (const float4*)(we + c * ED_DIM);
    const float4 w0 = w4[0], w1 = w4[1], w2 = w4[2], w3 = w4[3];
    const float attc = att[c];
    const float bc   = bias[c];
    const float xrc  = xr[(size_t)n * HC + c];
    const int lane16  = c & 15;
    const int segbase = (t & 63) & 48;   // 16-lane segment base within wave

    const int rs = rowstart[n], re = rowstart[n + 1];
    float l = 0.f, acc = 0.f;

    if (rs < re) {
        const int last = re - 1;
        const int q0 = rs;
        const int q1 = min(rs + 1, last);
        const int q2 = min(rs + 2, last);
        const int s0 = src_s[q0];
        const int s1 = src_s[q1];
        int   sP2 = src_s[q2];                    // src for p+2
        float xlA = xl[(size_t)s0 * HC + c];      // xl for p
        float xlB = xl[(size_t)s1 * HC + c];      // xl for p+1
        const int e0 = SORTED ? q0 : perm[q0];
        const int e1 = SORTED ? q1 : perm[q1];
        float eaA = ea[(size_t)e0 * ED_DIM + lane16];
        float eaB = ea[(size_t)e1 * ED_DIM + lane16];

        for (int p = rs; p < re; ++p) {
            const float eav = eaA, xlv = xlA;
            eaA = eaB; xlA = xlB;
            // issue next loads (no intra-iteration dependencies)
            xlB = xl[(size_t)sP2 * HC + c];       // for p+2 (sP2 resolved last iter)
            sP2 = src_s[min(p + 3, last)];        // for p+3
            const int qn = min(p + 2, last);
            const int en = SORTED ? qn : perm[qn];
            eaB = ea[(size_t)en * ED_DIM + lane16];  // for p+2

            // em[c] = sum_j we[c][j] * ea[j], ea[j] broadcast via shfl
            float em;
            em  = w0.x * __shfl(eav, segbase + 0, 64);
            em += w0.y * __shfl(eav, segbase + 1, 64);
            em += w0.z * __shfl(eav, segbase + 2, 64);
            em += w0.w * __shfl(eav, segbase + 3, 64);
            em += w1.x * __shfl(eav, segbase + 4, 64);
            em += w1.y * __shfl(eav, segbase + 5, 64);
            em += w1.z * __shfl(eav, segbase + 6, 64);
            em += w1.w * __shfl(eav, segbase + 7, 64);
            em += w2.x * __shfl(eav, segbase + 8, 64);
            em += w2.y * __shfl(eav, segbase + 9, 64);
            em += w2.z * __shfl(eav, segbase + 10, 64);
            em += w2.w * __shfl(eav, segbase + 11, 64);
            em += w3.x * __shfl(eav, segbase + 12, 64);
            em += w3.y * __shfl(eav, segbase + 13, 64);
            em += w3.z * __shfl(eav, segbase + 14, 64);
            em += w3.w * __shfl(eav, segbase + 15, 64);

            float v = xlv + xrc + em;
            v = fmaxf(v, 0.f) + NEG_SLOPE * fminf(v, 0.f);
            v *= attc;
            v += __shfl_xor(v, 1);
            v += __shfl_xor(v, 2);
            v += __shfl_xor(v, 4);
            v += __shfl_xor(v, 8);   // logit for this head, all 16 lanes
            const float pt = __expf(v);
            acc += pt * xlv;
            l   += pt;
        }
    }
    float o = acc / (l + 1e-16f) + bc;
    if (relu) o = fmaxf(o, 0.f);
    out[(size_t)n * HC + c] = o;
}

extern "C" void kernel_launch(void* const* d_in, const int* in_sizes, int n_in,
                              void* d_out, int out_size, void* d_ws, size_t ws_size,
                              hipStream_t stream) {
    (void)in_sizes; (void)n_in; (void)out_size;
    const float* x     = (const float*)d_in[0];
    const int*   ei    = (const int*)d_in[1];
    const float* eattr = (const float*)d_in[2];
    const int* srcp = ei;
    const int* dstp = ei + N_EDGES;

    // workspace layout
    float* h      = (float*)d_ws;                            // N*80
    float* xl     = h  + (size_t)N_NODES*HC;                 // N*80
    float* xr     = xl + (size_t)N_NODES*HC;                 // N*80
    int* rowstart = (int*)(xr + (size_t)N_NODES*HC);         // N+1
    int* cursor   = rowstart + (N_NODES + 1);                // N
    int* perm     = cursor + N_NODES;                        // E
    int* src_s    = perm + N_EDGES;                          // E
    int* partial  = src_s + N_EDGES;                         // SCAN_G
    int* blockoff = partial + SCAN_G;                        // SCAN_G
    int* dhist    = blockoff + SCAN_G;                       // DBIN
    int* dcur     = dhist + DBIN;                            // DBIN
    int* nodeord  = dcur + DBIN;                             // N
    float* eattr_s = (float*)(nodeord + N_NODES);            // E*16 (optional)
    float* outp   = (float*)d_out;

    const size_t need_sorted = (size_t)((char*)(eattr_s + (size_t)N_EDGES * ED_DIM) - (char*)d_ws);
    const bool use_sorted = (ws_size >= need_sorted);

    const dim3 bx(320);
    const dim3 gx((N_NODES + 63) / 64);
    const dim3 gf((N_NODES + 3) / 4);
    const dim3 geb((N_EDGES + 255) / 256);
    const dim3 gnb((N_NODES + 255) / 256);

    // ---- build CSR by destination + degree-sorted node order (once) ----
    hipMemsetAsync(cursor, 0, (size_t)N_NODES * sizeof(int), stream);
    hipMemsetAsync(dhist, 0, DBIN * sizeof(int), stream);
    k_hist<<<geb, 256, 0, stream>>>(dstp, cursor);
    k_part<<<SCAN_G, SCAN_B, 0, stream>>>(cursor, partial);
    k_scanp<<<1, 512, 0, stream>>>(partial, blockoff, rowstart);
    k_apply<<<SCAN_G, SCAN_B, 0, stream>>>(cursor, blockoff, rowstart);
    k_deghist<<<gnb, 256, 0, stream>>>(cursor, dhist);
    k_degoff<<<1, 64, 0, stream>>>(dhist, dcur);
    k_degplace<<<gnb, 256, 0, stream>>>(cursor, dcur, nodeord);
    hipMemsetAsync(cursor, 0, (size_t)N_NODES * sizeof(int), stream);
    k_place<<<geb, 256, 0, stream>>>(srcp, dstp, rowstart, cursor, perm, src_s);
    if (use_sorted) {
        k_permea<<<(N_EDGES * 4 + 255) / 256, 256, 0, stream>>>(eattr, perm, eattr_s);
    }

    for (int L = 0; L < 3; ++L) {
        const float* in   = (L == 0) ? x : h;
        float*       oacc = (L == 2) ? outp : h;
        const float* wl   = (const float*)d_in[3 + L*7 + 0];
        const float* bl   = (const float*)d_in[3 + L*7 + 1];
        const float* wr   = (const float*)d_in[3 + L*7 + 2];
        const float* br   = (const float*)d_in[3 + L*7 + 3];
        const float* we   = (const float*)d_in[3 + L*7 + 4];
        const float* att  = (const float*)d_in[3 + L*7 + 5];
        const float* bias = (const float*)d_in[3 + L*7 + 6];

        if (L == 0) {
            k_xform2<F_IN><<<gx, bx, 0, stream>>>(in, wl, bl, wr, br, xl, xr, N_NODES);
        } else {
            k_xform2<HC><<<gx, bx, 0, stream>>>(in, wl, bl, wr, br, xl, xr, N_NODES);
        }
        if (use_sorted) {
            k_fused3<true><<<gf, bx, 0, stream>>>(xl, xr, eattr_s, we, att, perm,
                                                  src_s, rowstart, nodeord, bias,
                                                  oacc, (L < 2) ? 1 : 0);
        } else {
            k_fused3<false><<<gf, bx, 0, stream>>>(xl, xr, eattr, we, att, perm,
                                                   src_s, rowstart, nodeord, bias,
                                                   oacc, (L < 2) ? 1 : 0);
        }
    }
}

// Round 8
// 1091.951 us; speedup vs baseline: 1.2797x; 1.2235x over previous
//
#include <hip/hip_runtime.h>
#include <hip/hip_bf16.h>
#include <math.h>

#define N_NODES 100000
#define N_EDGES 1000000
#define F_IN    128
#define ED_DIM  16
#define H_HEADS 5
#define C_CH    16
#define HC      80
#define NEG_SLOPE 0.2f

#define SCAN_B 256
#define SCAN_G ((N_NODES + SCAN_B - 1) / SCAN_B)   // 391
#define DBIN 64
#define EPAD 8   // padding entries on perm/src_s; 4 pad rows on eattr_s

// ================= CSR build (graph is static across layers) =================

__global__ void k_hist(const int* __restrict__ dst, int* __restrict__ count) {
    const int e = blockIdx.x * 256 + threadIdx.x;
    if (e < N_EDGES) atomicAdd(count + dst[e], 1);
}

__global__ __launch_bounds__(SCAN_B) void k_part(const int* __restrict__ count,
                                                 int* __restrict__ partial) {
    const int i = blockIdx.x * SCAN_B + threadIdx.x;
    int v = (i < N_NODES) ? count[i] : 0;
    const int lane = threadIdx.x & 63;
    const int w    = threadIdx.x >> 6;
    __shared__ int ws[SCAN_B / 64];
    #pragma unroll
    for (int o = 32; o > 0; o >>= 1) v += __shfl_down(v, o, 64);
    if (lane == 0) ws[w] = v;
    __syncthreads();
    if (threadIdx.x == 0) {
        int s = 0;
        #pragma unroll
        for (int k = 0; k < SCAN_B / 64; ++k) s += ws[k];
        partial[blockIdx.x] = s;
    }
}

__global__ __launch_bounds__(512) void k_scanp(const int* __restrict__ partial,
                                               int* __restrict__ blockoff,
                                               int* __restrict__ rowstart) {
    __shared__ int s[512];
    const int t = threadIdx.x;
    int v = (t < SCAN_G) ? partial[t] : 0;
    s[t] = v;
    __syncthreads();
    for (int o = 1; o < 512; o <<= 1) {
        int u = (t >= o) ? s[t - o] : 0;
        __syncthreads();
        s[t] += u;
        __syncthreads();
    }
    if (t < SCAN_G) blockoff[t] = (t == 0) ? 0 : s[t - 1];
    if (t == 0) rowstart[N_NODES] = s[511];
}

__global__ __launch_bounds__(SCAN_B) void k_apply(const int* __restrict__ count,
                                                  const int* __restrict__ blockoff,
                                                  int* __restrict__ rowstart) {
    __shared__ int s[SCAN_B];
    const int i = blockIdx.x * SCAN_B + threadIdx.x;
    const int t = threadIdx.x;
    const int v = (i < N_NODES) ? count[i] : 0;
    s[t] = v;
    __syncthreads();
    for (int o = 1; o < SCAN_B; o <<= 1) {
        int u = (t >= o) ? s[t - o] : 0;
        __syncthreads();
        s[t] += u;
        __syncthreads();
    }
    if (i < N_NODES) rowstart[i] = blockoff[blockIdx.x] + (s[t] - v);
}

__global__ void k_place(const int* __restrict__ src, const int* __restrict__ dst,
                        const int* __restrict__ rowstart, int* __restrict__ cursor,
                        int* __restrict__ perm, int* __restrict__ src_s) {
    const int e = blockIdx.x * 256 + threadIdx.x;
    if (e >= N_EDGES) return;
    const int d = dst[e];
    const int pos = rowstart[d] + atomicAdd(cursor + d, 1);
    perm[pos]  = e;
    src_s[pos] = src[e];
}

// pre-permute edge attrs into CSR order (once; reused by all 3 layers)
__global__ void k_permea(const float* __restrict__ eattr, const int* __restrict__ perm,
                         float* __restrict__ out) {
    const int i = blockIdx.x * 256 + threadIdx.x;   // over E*4 float4s
    if (i >= N_EDGES * 4) return;
    const int p = i >> 2;
    const int r = i & 3;
    const int e = perm[p];
    ((float4*)out)[i] = ((const float4*)eattr)[(size_t)e * 4 + r];
}

// ====== degree-bucket counting sort of nodes (descending degree) =============
__global__ __launch_bounds__(256) void k_deghist(const int* __restrict__ cnt,
                                                 int* __restrict__ dhist) {
    __shared__ int lh[DBIN];
    const int t = threadIdx.x;
    if (t < DBIN) lh[t] = 0;
    __syncthreads();
    const int n = blockIdx.x * 256 + t;
    if (n < N_NODES) atomicAdd(&lh[min(cnt[n], DBIN - 1)], 1);
    __syncthreads();
    if (t < DBIN && lh[t] > 0) atomicAdd(dhist + t, lh[t]);
}

// also zeroes the perm/src_s padding (ws is re-poisoned before every launch)
__global__ void k_degoff(const int* __restrict__ dhist, int* __restrict__ dcur,
                         int* __restrict__ perm, int* __restrict__ src_s) {
    if (threadIdx.x == 0) {
        int off = 0;
        for (int b = DBIN - 1; b >= 0; --b) { dcur[b] = off; off += dhist[b]; }
        for (int i = 0; i < EPAD; ++i) {
            perm[N_EDGES + i]  = 0;
            src_s[N_EDGES + i] = 0;
        }
    }
}

__global__ __launch_bounds__(256) void k_degplace(const int* __restrict__ cnt,
                                                  int* __restrict__ dcur,
                                                  int* __restrict__ nodeord) {
    __shared__ int lh[DBIN];
    __shared__ int base[DBIN];
    const int t = threadIdx.x;
    if (t < DBIN) lh[t] = 0;
    __syncthreads();
    const int n = blockIdx.x * 256 + t;
    int b = 0, r = 0;
    if (n < N_NODES) {
        b = min(cnt[n], DBIN - 1);
        r = atomicAdd(&lh[b], 1);
    }
    __syncthreads();
    if (t < DBIN && lh[t] > 0) base[t] = atomicAdd(dcur + t, lh[t]);
    __syncthreads();
    if (n < N_NODES) nodeord[base[b] + r] = n;
}

// ====== fused dual node transform: xl = A@WL^T+bL, xr = A@WR^T+bR ============
template<int DIN>
__global__ __launch_bounds__(320) void k_xform2(
    const float* __restrict__ A,
    const float* __restrict__ WL, const float* __restrict__ bL,
    const float* __restrict__ WR, const float* __restrict__ bR,
    float* __restrict__ outL, float* __restrict__ outR, int nn) {
    __shared__ float As[16][68];
    __shared__ float WsL[16][80];
    __shared__ float WsR[16][80];
    const int t  = threadIdx.x;
    const int n0 = blockIdx.x * 64;
    const int tn = (t & 15) * 4;
    const int tj = (t >> 4) * 4;
    float4 accL[4], accR[4];
    #pragma unroll
    for (int u = 0; u < 4; ++u) {
        accL[u] = make_float4(0.f, 0.f, 0.f, 0.f);
        accR[u] = make_float4(0.f, 0.f, 0.f, 0.f);
    }

    for (int k0 = 0; k0 < DIN; k0 += 16) {
        __syncthreads();
        for (int i = t; i < 64*16; i += 320) {
            int nl = i >> 4, kk = i & 15;
            int n = n0 + nl;
            As[kk][nl] = (n < nn) ? A[(size_t)n*DIN + k0 + kk] : 0.f;
        }
        for (int i = t; i < 80*16; i += 320) {
            int jj = i >> 4, kk = i & 15;
            WsL[kk][jj] = WL[(size_t)jj*DIN + k0 + kk];
            WsR[kk][jj] = WR[(size_t)jj*DIN + k0 + kk];
        }
        __syncthreads();
        #pragma unroll
        for (int k = 0; k < 16; ++k) {
            const float4 av = *(const float4*)&As[k][tn];
            const float4 wl = *(const float4*)&WsL[k][tj];
            const float4 wr = *(const float4*)&WsR[k][tj];
            accL[0].x += av.x*wl.x; accL[0].y += av.x*wl.y; accL[0].z += av.x*wl.z; accL[0].w += av.x*wl.w;
            accL[1].x += av.y*wl.x; accL[1].y += av.y*wl.y; accL[1].z += av.y*wl.z; accL[1].w += av.y*wl.w;
            accL[2].x += av.z*wl.x; accL[2].y += av.z*wl.y; accL[2].z += av.z*wl.z; accL[2].w += av.z*wl.w;
            accL[3].x += av.w*wl.x; accL[3].y += av.w*wl.y; accL[3].z += av.w*wl.z; accL[3].w += av.w*wl.w;
            accR[0].x += av.x*wr.x; accR[0].y += av.x*wr.y; accR[0].z += av.x*wr.z; accR[0].w += av.x*wr.w;
            accR[1].x += av.y*wr.x; accR[1].y += av.y*wr.y; accR[1].z += av.y*wr.z; accR[1].w += av.y*wr.w;
            accR[2].x += av.z*wr.x; accR[2].y += av.z*wr.y; accR[2].z += av.z*wr.z; accR[2].w += av.z*wr.w;
            accR[3].x += av.w*wr.x; accR[3].y += av.w*wr.y; accR[3].z += av.w*wr.z; accR[3].w += av.w*wr.w;
        }
    }
    const float4 bvL = *(const float4*)(bL + tj);
    const float4 bvR = *(const float4*)(bR + tj);
    #pragma unroll
    for (int u = 0; u < 4; ++u) {
        int n = n0 + tn + u;
        if (n < nn) {
            float4 o;
            o.x = accL[u].x + bvL.x; o.y = accL[u].y + bvL.y;
            o.z = accL[u].z + bvL.z; o.w = accL[u].w + bvL.w;
            *(float4*)(outL + (size_t)n*HC + tj) = o;
            o.x = accR[u].x + bvR.x; o.y = accR[u].y + bvR.y;
            o.z = accR[u].z + bvR.z; o.w = accR[u].w + bvR.w;
            *(float4*)(outR + (size_t)n*HC + tj) = o;
        }
    }
}

// cross-lane helpers: compile-time ds_swizzle, zero VALU overhead
#define SWZ(v, imm) __int_as_float(__builtin_amdgcn_ds_swizzle(__float_as_int(v), (imm)))
// broadcast lane ((lane&0x10)|j) within each 32-lane half: imm = (j<<5)|0x10
#define BC(v, j) SWZ(v, ((j) << 5) | 0x10)

// ====== fused attention v4: 1 node per 80-thread group ======================
// thread = channel c (head = c>>4). Lane-sliced eattr (thread loads ea[c&15],
// 4 B); em[c] via 16 immediate ds_swizzle broadcasts. All hot-loop indexing
// 32-bit; no clamps (perm/src_s/eattr_s padded; tail prefetches load garbage
// that is never consumed by the math).
template<bool SORTED>
__global__ __launch_bounds__(320) void k_fused4(
    const float* __restrict__ xl, const float* __restrict__ xr,
    const float* __restrict__ ea,   // eattr_s if SORTED, raw eattr otherwise
    const float* __restrict__ we, const float* __restrict__ att,
    const int* __restrict__ perm, const int* __restrict__ src_s,
    const int* __restrict__ rowstart, const int* __restrict__ nodeord,
    const float* __restrict__ bias, float* __restrict__ out, int relu) {
    const int t = threadIdx.x;
    const int group = t / 80;
    const int c = t - group * 80;
    const int idx = blockIdx.x * 4 + group;
    if (idx >= N_NODES) return;
    const int n = nodeord[idx];

    const float4* w4 = (const float4*)(we + c * ED_DIM);
    const float4 w0 = w4[0], w1 = w4[1], w2 = w4[2], w3 = w4[3];
    const float attc = att[c];
    const float bc   = bias[c];
    const float xrc  = xr[n * HC + c];
    const int lane16 = c & 15;

    const int rs = rowstart[n], re = rowstart[n + 1];
    float l = 0.f, acc = 0.f;

    if (rs < re) {
        // pipeline preamble (pads make rs+3 always in-bounds)
        const int s0 = src_s[rs];
        const int s1 = src_s[rs + 1];
        int   sP2 = src_s[rs + 2];                    // src for p+2
        float xlA = xl[s0 * HC + c];                  // xl for p
        float xlB = xl[s1 * HC + c];                  // xl for p+1
        const int e0 = SORTED ? rs       : perm[rs];
        const int e1 = SORTED ? (rs + 1) : perm[rs + 1];
        float eaA = ea[e0 * ED_DIM + lane16];
        float eaB = ea[e1 * ED_DIM + lane16];

        for (int p = rs; p < re; ++p) {
            const float eav = eaA, xlv = xlA;
            eaA = eaB; xlA = xlB;
            // issue next loads (no intra-iteration dependent chains)
            xlB = xl[sP2 * HC + c];                   // for p+2
            sP2 = src_s[p + 3];                       // for p+3
            const int en = SORTED ? (p + 2) : perm[p + 2];
            eaB = ea[en * ED_DIM + lane16];           // for p+2

            // em[c] = sum_j we[c][j]*ea[j]; 4 partial chains
            float m0 = w0.x * BC(eav, 0)  + w0.y * BC(eav, 1)
                     + w0.z * BC(eav, 2)  + w0.w * BC(eav, 3);
            float m1 = w1.x * BC(eav, 4)  + w1.y * BC(eav, 5)
                     + w1.z * BC(eav, 6)  + w1.w * BC(eav, 7);
            float m2 = w2.x * BC(eav, 8)  + w2.y * BC(eav, 9)
                     + w2.z * BC(eav, 10) + w2.w * BC(eav, 11);
            float m3 = w3.x * BC(eav, 12) + w3.y * BC(eav, 13)
                     + w3.z * BC(eav, 14) + w3.w * BC(eav, 15);
            float v = xlv + xrc + ((m0 + m1) + (m2 + m3));
            v = fmaxf(v, 0.f) + NEG_SLOPE * fminf(v, 0.f);
            v *= attc;
            // 16-lane butterfly sum via immediate swizzles (xor 1,2,4,8)
            v += SWZ(v, 0x041F);
            v += SWZ(v, 0x081F);
            v += SWZ(v, 0x101F);
            v += SWZ(v, 0x201F);
            const float pt = __expf(v);
            acc += pt * xlv;
            l   += pt;
        }
    }
    float o = acc / (l + 1e-16f) + bc;
    if (relu) o = fmaxf(o, 0.f);
    out[n * HC + c] = o;
}

extern "C" void kernel_launch(void* const* d_in, const int* in_sizes, int n_in,
                              void* d_out, int out_size, void* d_ws, size_t ws_size,
                              hipStream_t stream) {
    (void)in_sizes; (void)n_in; (void)out_size;
    const float* x     = (const float*)d_in[0];
    const int*   ei    = (const int*)d_in[1];
    const float* eattr = (const float*)d_in[2];
    const int* srcp = ei;
    const int* dstp = ei + N_EDGES;

    // workspace layout
    float* h      = (float*)d_ws;                            // N*80
    float* xl     = h  + (size_t)N_NODES*HC;                 // N*80
    float* xr     = xl + (size_t)N_NODES*HC;                 // N*80
    int* rowstart = (int*)(xr + (size_t)N_NODES*HC);         // N+1
    int* cursor   = rowstart + (N_NODES + 1);                // N
    int* perm     = cursor + N_NODES;                        // E + EPAD
    int* src_s    = perm + N_EDGES + EPAD;                   // E + EPAD
    int* partial  = src_s + N_EDGES + EPAD;                  // SCAN_G
    int* blockoff = partial + SCAN_G;                        // SCAN_G
    int* dhist    = blockoff + SCAN_G;                       // DBIN
    int* dcur     = dhist + DBIN;                            // DBIN
    int* nodeord  = dcur + DBIN;                             // N
    float* eattr_s = (float*)(nodeord + N_NODES);            // (E+4)*16 (optional)
    float* outp   = (float*)d_out;

    const size_t need_sorted =
        (size_t)((char*)(eattr_s + (size_t)(N_EDGES + 4) * ED_DIM) - (char*)d_ws);
    const bool use_sorted = (ws_size >= need_sorted);

    const dim3 bx(320);
    const dim3 gx((N_NODES + 63) / 64);
    const dim3 gf((N_NODES + 3) / 4);
    const dim3 geb((N_EDGES + 255) / 256);
    const dim3 gnb((N_NODES + 255) / 256);

    // ---- build CSR by destination + degree-sorted node order (once) ----
    hipMemsetAsync(cursor, 0, (size_t)N_NODES * sizeof(int), stream);
    hipMemsetAsync(dhist, 0, DBIN * sizeof(int), stream);
    k_hist<<<geb, 256, 0, stream>>>(dstp, cursor);
    k_part<<<SCAN_G, SCAN_B, 0, stream>>>(cursor, partial);
    k_scanp<<<1, 512, 0, stream>>>(partial, blockoff, rowstart);
    k_apply<<<SCAN_G, SCAN_B, 0, stream>>>(cursor, blockoff, rowstart);
    k_deghist<<<gnb, 256, 0, stream>>>(cursor, dhist);
    k_degoff<<<1, 64, 0, stream>>>(dhist, dcur, perm, src_s);
    k_degplace<<<gnb, 256, 0, stream>>>(cursor, dcur, nodeord);
    hipMemsetAsync(cursor, 0, (size_t)N_NODES * sizeof(int), stream);
    k_place<<<geb, 256, 0, stream>>>(srcp, dstp, rowstart, cursor, perm, src_s);
    if (use_sorted) {
        k_permea<<<(N_EDGES * 4 + 255) / 256, 256, 0, stream>>>(eattr, perm, eattr_s);
    }

    for (int L = 0; L < 3; ++L) {
        const float* in   = (L == 0) ? x : h;
        float*       oacc = (L == 2) ? outp : h;
        const float* wl   = (const float*)d_in[3 + L*7 + 0];
        const float* bl   = (const float*)d_in[3 + L*7 + 1];
        const float* wr   = (const float*)d_in[3 + L*7 + 2];
        const float* br   = (const float*)d_in[3 + L*7 + 3];
        const float* we   = (const float*)d_in[3 + L*7 + 4];
        const float* att  = (const float*)d_in[3 + L*7 + 5];
        const float* bias = (const float*)d_in[3 + L*7 + 6];

        if (L == 0) {
            k_xform2<F_IN><<<gx, bx, 0, stream>>>(in, wl, bl, wr, br, xl, xr, N_NODES);
        } else {
            k_xform2<HC><<<gx, bx, 0, stream>>>(in, wl, bl, wr, br, xl, xr, N_NODES);
        }
        if (use_sorted) {
            k_fused4<true><<<gf, bx, 0, stream>>>(xl, xr, eattr_s, we, att, perm,
                                                  src_s, rowstart, nodeord, bias,
                                                  oacc, (L < 2) ? 1 : 0);
        } else {
            k_fused4<false><<<gf, bx, 0, stream>>>(xl, xr, eattr, we, att, perm,
                                                   src_s, rowstart, nodeord, bias,
                                                   oacc, (L < 2) ? 1 : 0);
        }
    }
}

// Round 9
// 980.507 us; speedup vs baseline: 1.4252x; 1.1137x over previous
//
#include <hip/hip_runtime.h>
#include <hip/hip_bf16.h>
#include <math.h>

#define N_NODES 100000
#define N_EDGES 1000000
#define F_IN    128
#define ED_DIM  16
#define H_HEADS 5
#define C_CH    16
#define HC      80
#define NEG_SLOPE 0.2f

#define SCAN_B 256
#define SCAN_G ((N_NODES + SCAN_B - 1) / SCAN_B)   // 391
#define DBIN 64
#define EPAD 8   // padding entries on src_s/perm; 8 pad rows on eattr_s

// ================= CSR build (graph is static across layers) =================

__global__ void k_hist(const int* __restrict__ dst, int* __restrict__ count) {
    const int e = blockIdx.x * 256 + threadIdx.x;
    if (e < N_EDGES) atomicAdd(count + dst[e], 1);
}

__global__ __launch_bounds__(SCAN_B) void k_part(const int* __restrict__ count,
                                                 int* __restrict__ partial) {
    const int i = blockIdx.x * SCAN_B + threadIdx.x;
    int v = (i < N_NODES) ? count[i] : 0;
    const int lane = threadIdx.x & 63;
    const int w    = threadIdx.x >> 6;
    __shared__ int ws[SCAN_B / 64];
    #pragma unroll
    for (int o = 32; o > 0; o >>= 1) v += __shfl_down(v, o, 64);
    if (lane == 0) ws[w] = v;
    __syncthreads();
    if (threadIdx.x == 0) {
        int s = 0;
        #pragma unroll
        for (int k = 0; k < SCAN_B / 64; ++k) s += ws[k];
        partial[blockIdx.x] = s;
    }
}

__global__ __launch_bounds__(512) void k_scanp(const int* __restrict__ partial,
                                               int* __restrict__ blockoff,
                                               int* __restrict__ rowstart) {
    __shared__ int s[512];
    const int t = threadIdx.x;
    int v = (t < SCAN_G) ? partial[t] : 0;
    s[t] = v;
    __syncthreads();
    for (int o = 1; o < 512; o <<= 1) {
        int u = (t >= o) ? s[t - o] : 0;
        __syncthreads();
        s[t] += u;
        __syncthreads();
    }
    if (t < SCAN_G) blockoff[t] = (t == 0) ? 0 : s[t - 1];
    if (t == 0) rowstart[N_NODES] = s[511];
}

__global__ __launch_bounds__(SCAN_B) void k_apply(const int* __restrict__ count,
                                                  const int* __restrict__ blockoff,
                                                  int* __restrict__ rowstart) {
    __shared__ int s[SCAN_B];
    const int i = blockIdx.x * SCAN_B + threadIdx.x;
    const int t = threadIdx.x;
    const int v = (i < N_NODES) ? count[i] : 0;
    s[t] = v;
    __syncthreads();
    for (int o = 1; o < SCAN_B; o <<= 1) {
        int u = (t >= o) ? s[t - o] : 0;
        __syncthreads();
        s[t] += u;
        __syncthreads();
    }
    if (i < N_NODES) rowstart[i] = blockoff[blockIdx.x] + (s[t] - v);
}

// place edge into CSR slot; src_s stores src*HC (pre-scaled for the hot loop);
// if COPY, also copy the 64B eattr row into CSR order (replaces k_permea pass)
template<bool COPY>
__global__ void k_place(const int* __restrict__ src, const int* __restrict__ dst,
                        const int* __restrict__ rowstart, int* __restrict__ cursor,
                        int* __restrict__ perm, int* __restrict__ src_s,
                        const float* __restrict__ eattr, float* __restrict__ eattr_s) {
    const int e = blockIdx.x * 256 + threadIdx.x;
    if (e >= N_EDGES) return;
    const int d = dst[e];
    const int pos = rowstart[d] + atomicAdd(cursor + d, 1);
    src_s[pos] = src[e] * HC;
    if (COPY) {
        const float4* s4 = (const float4*)(eattr + (size_t)e * ED_DIM);
        float4* d4 = (float4*)(eattr_s + (size_t)pos * ED_DIM);
        d4[0] = s4[0]; d4[1] = s4[1]; d4[2] = s4[2]; d4[3] = s4[3];
    } else {
        perm[pos] = e;
    }
}

// ====== degree-bucket counting sort of nodes (descending degree) =============
__global__ __launch_bounds__(256) void k_deghist(const int* __restrict__ cnt,
                                                 int* __restrict__ dhist) {
    __shared__ int lh[DBIN];
    const int t = threadIdx.x;
    if (t < DBIN) lh[t] = 0;
    __syncthreads();
    const int n = blockIdx.x * 256 + t;
    if (n < N_NODES) atomicAdd(&lh[min(cnt[n], DBIN - 1)], 1);
    __syncthreads();
    if (t < DBIN && lh[t] > 0) atomicAdd(dhist + t, lh[t]);
}

// also zeroes the perm/src_s padding (ws is re-poisoned before every launch)
__global__ void k_degoff(const int* __restrict__ dhist, int* __restrict__ dcur,
                         int* __restrict__ perm, int* __restrict__ src_s) {
    if (threadIdx.x == 0) {
        int off = 0;
        for (int b = DBIN - 1; b >= 0; --b) { dcur[b] = off; off += dhist[b]; }
        for (int i = 0; i < EPAD; ++i) {
            perm[N_EDGES + i]  = 0;
            src_s[N_EDGES + i] = 0;
        }
    }
}

__global__ __launch_bounds__(256) void k_degplace(const int* __restrict__ cnt,
                                                  int* __restrict__ dcur,
                                                  int* __restrict__ nodeord) {
    __shared__ int lh[DBIN];
    __shared__ int base[DBIN];
    const int t = threadIdx.x;
    if (t < DBIN) lh[t] = 0;
    __syncthreads();
    const int n = blockIdx.x * 256 + t;
    int b = 0, r = 0;
    if (n < N_NODES) {
        b = min(cnt[n], DBIN - 1);
        r = atomicAdd(&lh[b], 1);
    }
    __syncthreads();
    if (t < DBIN && lh[t] > 0) base[t] = atomicAdd(dcur + t, lh[t]);
    __syncthreads();
    if (n < N_NODES) nodeord[base[b] + r] = n;
}

// ====== fused dual node transform: xl = A@WL^T+bL, xr = A@WR^T+bR ============
template<int DIN>
__global__ __launch_bounds__(320) void k_xform2(
    const float* __restrict__ A,
    const float* __restrict__ WL, const float* __restrict__ bL,
    const float* __restrict__ WR, const float* __restrict__ bR,
    float* __restrict__ outL, float* __restrict__ outR, int nn) {
    __shared__ float As[16][68];
    __shared__ float WsL[16][80];
    __shared__ float WsR[16][80];
    const int t  = threadIdx.x;
    const int n0 = blockIdx.x * 64;
    const int tn = (t & 15) * 4;
    const int tj = (t >> 4) * 4;
    float4 accL[4], accR[4];
    #pragma unroll
    for (int u = 0; u < 4; ++u) {
        accL[u] = make_float4(0.f, 0.f, 0.f, 0.f);
        accR[u] = make_float4(0.f, 0.f, 0.f, 0.f);
    }

    for (int k0 = 0; k0 < DIN; k0 += 16) {
        __syncthreads();
        for (int i = t; i < 64*16; i += 320) {
            int nl = i >> 4, kk = i & 15;
            int n = n0 + nl;
            As[kk][nl] = (n < nn) ? A[(size_t)n*DIN + k0 + kk] : 0.f;
        }
        for (int i = t; i < 80*16; i += 320) {
            int jj = i >> 4, kk = i & 15;
            WsL[kk][jj] = WL[(size_t)jj*DIN + k0 + kk];
            WsR[kk][jj] = WR[(size_t)jj*DIN + k0 + kk];
        }
        __syncthreads();
        #pragma unroll
        for (int k = 0; k < 16; ++k) {
            const float4 av = *(const float4*)&As[k][tn];
            const float4 wl = *(const float4*)&WsL[k][tj];
            const float4 wr = *(const float4*)&WsR[k][tj];
            accL[0].x += av.x*wl.x; accL[0].y += av.x*wl.y; accL[0].z += av.x*wl.z; accL[0].w += av.x*wl.w;
            accL[1].x += av.y*wl.x; accL[1].y += av.y*wl.y; accL[1].z += av.y*wl.z; accL[1].w += av.y*wl.w;
            accL[2].x += av.z*wl.x; accL[2].y += av.z*wl.y; accL[2].z += av.z*wl.z; accL[2].w += av.z*wl.w;
            accL[3].x += av.w*wl.x; accL[3].y += av.w*wl.y; accL[3].z += av.w*wl.z; accL[3].w += av.w*wl.w;
            accR[0].x += av.x*wr.x; accR[0].y += av.x*wr.y; accR[0].z += av.x*wr.z; accR[0].w += av.x*wr.w;
            accR[1].x += av.y*wr.x; accR[1].y += av.y*wr.y; accR[1].z += av.y*wr.z; accR[1].w += av.y*wr.w;
            accR[2].x += av.z*wr.x; accR[2].y += av.z*wr.y; accR[2].z += av.z*wr.z; accR[2].w += av.z*wr.w;
            accR[3].x += av.w*wr.x; accR[3].y += av.w*wr.y; accR[3].z += av.w*wr.z; accR[3].w += av.w*wr.w;
        }
    }
    const float4 bvL = *(const float4*)(bL + tj);
    const float4 bvR = *(const float4*)(bR + tj);
    #pragma unroll
    for (int u = 0; u < 4; ++u) {
        int n = n0 + tn + u;
        if (n < nn) {
            float4 o;
            o.x = accL[u].x + bvL.x; o.y = accL[u].y + bvL.y;
            o.z = accL[u].z + bvL.z; o.w = accL[u].w + bvL.w;
            *(float4*)(outL + (size_t)n*HC + tj) = o;
            o.x = accR[u].x + bvR.x; o.y = accR[u].y + bvR.y;
            o.z = accR[u].z + bvR.z; o.w = accR[u].w + bvR.w;
            *(float4*)(outR + (size_t)n*HC + tj) = o;
        }
    }
}

// cross-lane helpers: compile-time ds_swizzle, zero VALU overhead
#define SWZ(v, imm) __int_as_float(__builtin_amdgcn_ds_swizzle(__float_as_int(v), (imm)))
// broadcast lane ((lane&0x10)|j) within each 32-lane half: imm = (j<<5)|0x10
#define BC(v, j) SWZ(v, ((j) << 5) | 0x10)

// per-edge logit+exp+accumulate (shared by both unroll slots)
__device__ __forceinline__ void edge_step(
    float eav, float xlv, float xrc, float attc,
    const float4& w0, const float4& w1, const float4& w2, const float4& w3,
    float gate, float& acc, float& l) {
    float m0 = w0.x * BC(eav, 0)  + w0.y * BC(eav, 1)
             + w0.z * BC(eav, 2)  + w0.w * BC(eav, 3);
    float m1 = w1.x * BC(eav, 4)  + w1.y * BC(eav, 5)
             + w1.z * BC(eav, 6)  + w1.w * BC(eav, 7);
    float m2 = w2.x * BC(eav, 8)  + w2.y * BC(eav, 9)
             + w2.z * BC(eav, 10) + w2.w * BC(eav, 11);
    float m3 = w3.x * BC(eav, 12) + w3.y * BC(eav, 13)
             + w3.z * BC(eav, 14) + w3.w * BC(eav, 15);
    float v = xlv + xrc + ((m0 + m1) + (m2 + m3));
    v = fmaxf(v, 0.f) + NEG_SLOPE * fminf(v, 0.f);
    v *= attc;
    v += SWZ(v, 0x041F);
    v += SWZ(v, 0x081F);
    v += SWZ(v, 0x101F);
    v += SWZ(v, 0x201F);
    const float pt = __expf(v) * gate;
    acc += pt * xlv;
    l   += pt;
}

// ====== fused attention v5: 1 node per 80-thread group, 2 edges/iter ========
// thread = channel c (head = c>>4). Lane-sliced eattr; em via immediate
// ds_swizzle broadcasts. 2-edge unroll with 4-deep prefetch pipeline:
// all loads issued at iteration top, no intra-iteration dependent chains.
// src_s is pre-scaled by HC. Pads make all prefetches in-bounds; pad-driven
// garbage is bounded (exp finite) and killed by gate=0.
template<bool SORTED>
__global__ __launch_bounds__(320) void k_fused5(
    const float* __restrict__ xl, const float* __restrict__ xr,
    const float* __restrict__ ea,   // eattr_s if SORTED, raw eattr otherwise
    const float* __restrict__ we, const float* __restrict__ att,
    const int* __restrict__ perm, const int* __restrict__ src_s,
    const int* __restrict__ rowstart, const int* __restrict__ nodeord,
    const float* __restrict__ bias, float* __restrict__ out, int relu) {
    const int t = threadIdx.x;
    const int group = t / 80;
    const int c = t - group * 80;
    const int idx = blockIdx.x * 4 + group;
    if (idx >= N_NODES) return;
    const int n = nodeord[idx];

    const float4* w4 = (const float4*)(we + c * ED_DIM);
    const float4 w0 = w4[0], w1 = w4[1], w2 = w4[2], w3 = w4[3];
    const float attc = att[c];
    const float bc   = bias[c];
    const float xrc  = xr[n * HC + c];
    const int lane16 = c & 15;

    const int rs = rowstart[n], re = rowstart[n + 1];
    float l = 0.f, acc = 0.f;

    if (rs < re) {
        // preamble: values for p, p+1 in flight; src offsets for p+2, p+3
        const int o0 = src_s[rs];
        const int o1 = src_s[rs + 1];
        int sA = src_s[rs + 2];
        int sB = src_s[rs + 3];
        float xlA = xl[o0 + c];
        float xlB = xl[o1 + c];
        const int e0 = SORTED ? rs       : perm[rs];
        const int e1 = SORTED ? (rs + 1) : perm[rs + 1];
        float eaA = ea[e0 * ED_DIM + lane16];
        float eaB = ea[e1 * ED_DIM + lane16];

        for (int p = rs; p < re; p += 2) {
            const float xl0 = xlA, xl1 = xlB;
            const float ea0 = eaA, ea1 = eaB;
            // issue next loads (for p+2, p+3); no dependent chains in-iter
            xlA = xl[sA + c];
            xlB = xl[sB + c];
            sA = src_s[p + 4];
            sB = src_s[p + 5];
            const int en0 = SORTED ? (p + 2) : perm[p + 2];
            const int en1 = SORTED ? (p + 3) : perm[p + 3];
            eaA = ea[en0 * ED_DIM + lane16];
            eaB = ea[en1 * ED_DIM + lane16];

            edge_step(ea0, xl0, xrc, attc, w0, w1, w2, w3, 1.f, acc, l);
            const float g1 = (p + 1 < re) ? 1.f : 0.f;
            edge_step(ea1, xl1, xrc, attc, w0, w1, w2, w3, g1, acc, l);
        }
    }
    float o = acc / (l + 1e-16f) + bc;
    if (relu) o = fmaxf(o, 0.f);
    out[n * HC + c] = o;
}

extern "C" void kernel_launch(void* const* d_in, const int* in_sizes, int n_in,
                              void* d_out, int out_size, void* d_ws, size_t ws_size,
                              hipStream_t stream) {
    (void)in_sizes; (void)n_in; (void)out_size;
    const float* x     = (const float*)d_in[0];
    const int*   ei    = (const int*)d_in[1];
    const float* eattr = (const float*)d_in[2];
    const int* srcp = ei;
    const int* dstp = ei + N_EDGES;

    // workspace layout
    float* h      = (float*)d_ws;                            // N*80
    float* xl     = h  + (size_t)N_NODES*HC;                 // N*80
    float* xr     = xl + (size_t)N_NODES*HC;                 // N*80
    int* rowstart = (int*)(xr + (size_t)N_NODES*HC);         // N+1
    int* cursor   = rowstart + (N_NODES + 1);                // N
    int* perm     = cursor + N_NODES;                        // E + EPAD
    int* src_s    = perm + N_EDGES + EPAD;                   // E + EPAD
    int* partial  = src_s + N_EDGES + EPAD;                  // SCAN_G
    int* blockoff = partial + SCAN_G;                        // SCAN_G
    int* dhist    = blockoff + SCAN_G;                       // DBIN
    int* dcur     = dhist + DBIN;                            // DBIN
    int* nodeord  = dcur + DBIN;                             // N
    float* eattr_s = (float*)(nodeord + N_NODES);            // (E+8)*16 (optional)
    float* outp   = (float*)d_out;

    const size_t need_sorted =
        (size_t)((char*)(eattr_s + (size_t)(N_EDGES + EPAD) * ED_DIM) - (char*)d_ws);
    const bool use_sorted = (ws_size >= need_sorted);

    const dim3 bx(320);
    const dim3 gx((N_NODES + 63) / 64);
    const dim3 gf((N_NODES + 3) / 4);
    const dim3 geb((N_EDGES + 255) / 256);
    const dim3 gnb((N_NODES + 255) / 256);

    // ---- build CSR by destination + degree-sorted node order (once) ----
    hipMemsetAsync(cursor, 0, (size_t)N_NODES * sizeof(int), stream);
    hipMemsetAsync(dhist, 0, DBIN * sizeof(int), stream);
    k_hist<<<geb, 256, 0, stream>>>(dstp, cursor);
    k_part<<<SCAN_G, SCAN_B, 0, stream>>>(cursor, partial);
    k_scanp<<<1, 512, 0, stream>>>(partial, blockoff, rowstart);
    k_apply<<<SCAN_G, SCAN_B, 0, stream>>>(cursor, blockoff, rowstart);
    k_deghist<<<gnb, 256, 0, stream>>>(cursor, dhist);
    k_degoff<<<1, 64, 0, stream>>>(dhist, dcur, perm, src_s);
    k_degplace<<<gnb, 256, 0, stream>>>(cursor, dcur, nodeord);
    hipMemsetAsync(cursor, 0, (size_t)N_NODES * sizeof(int), stream);
    if (use_sorted) {
        k_place<true><<<geb, 256, 0, stream>>>(srcp, dstp, rowstart, cursor,
                                               perm, src_s, eattr, eattr_s);
    } else {
        k_place<false><<<geb, 256, 0, stream>>>(srcp, dstp, rowstart, cursor,
                                                perm, src_s, eattr, eattr_s);
    }

    for (int L = 0; L < 3; ++L) {
        const float* in   = (L == 0) ? x : h;
        float*       oacc = (L == 2) ? outp : h;
        const float* wl   = (const float*)d_in[3 + L*7 + 0];
        const float* bl   = (const float*)d_in[3 + L*7 + 1];
        const float* wr   = (const float*)d_in[3 + L*7 + 2];
        const float* br   = (const float*)d_in[3 + L*7 + 3];
        const float* we   = (const float*)d_in[3 + L*7 + 4];
        const float* att  = (const float*)d_in[3 + L*7 + 5];
        const float* bias = (const float*)d_in[3 + L*7 + 6];

        if (L == 0) {
            k_xform2<F_IN><<<gx, bx, 0, stream>>>(in, wl, bl, wr, br, xl, xr, N_NODES);
        } else {
            k_xform2<HC><<<gx, bx, 0, stream>>>(in, wl, bl, wr, br, xl, xr, N_NODES);
        }
        if (use_sorted) {
            k_fused5<true><<<gf, bx, 0, stream>>>(xl, xr, eattr_s, we, att, perm,
                                                  src_s, rowstart, nodeord, bias,
                                                  oacc, (L < 2) ? 1 : 0);
        } else {
            k_fused5<false><<<gf, bx, 0, stream>>>(xl, xr, eattr, we, att, perm,
                                                   src_s, rowstart, nodeord, bias,
                                                   oacc, (L < 2) ? 1 : 0);
        }
    }
}